// Round 4
// baseline (444.645 us; speedup 1.0000x reference)
//
#include <hip/hip_runtime.h>

// LayerGCN: out = relu(bn2(relu(bn1( (D^-.5 (A>=.1) D^-.5) V @ W1 )) @ W2))
// B=4096, N=128, C_IN=64, C_HID=256, C_OUT=128.
// R4: transposed GEMM1 (h^T in regs, m lane-local) -> h/x1/dinv never touch LDS;
// k-permuted W1p AND W2p so all inter-GEMM handoffs are register repacks.
// LDS = vtt + BN shifts only (18.9 KB) -> 4 blocks/CU.

#define THRESH 0.1f
#define BN_EPS 1e-5f

typedef __attribute__((ext_vector_type(8))) short bf16x8;
typedef __attribute__((ext_vector_type(4))) float f32x4;

__device__ __forceinline__ unsigned short f2bf(float f) {
    union { float f; unsigned u; } x; x.f = f;
    unsigned r = x.u + 0x7FFFu + ((x.u >> 16) & 1u);   // RNE
    return (unsigned short)(r >> 16);
}

__device__ __forceinline__ unsigned cvt_pk(float lo, float hi) {
    unsigned r;
    asm("v_cvt_pk_bf16_f32 %0, %1, %2" : "=v"(r) : "v"(lo), "v"(hi));
    return r;
}

// ---------------- prep ----------------
// Shared k-permutation (within each 32-chunk): k' fields {T=k'>>5, gg=(k'>>3)&3,
// a=(k'>>2)&1, r=k'&3} <- k = 32T + 16a + 4gg + r. Register slot j of lane-group g
// holds logical k = 32T + 16(j>>2) + 4g + (j&3); contiguous-8 load of k' matches it.
// W1p[n][k'] = bf16(W1[k][n]*sc1[n])  (256x64),  W2p[n][k'] = bf16(W2[k][n]*sc2[n]) (128x256)
// sh1 = (b1-rm1)*sc1 + be1, sh2 = (b2-rm2)*sc2 + be2.
__global__ void gcn_prep(const float* __restrict__ W1, const float* __restrict__ b1,
                         const float* __restrict__ g1, const float* __restrict__ be1,
                         const float* __restrict__ rm1, const float* __restrict__ rv1,
                         const float* __restrict__ W2, const float* __restrict__ b2,
                         const float* __restrict__ g2, const float* __restrict__ be2,
                         const float* __restrict__ rm2, const float* __restrict__ rv2,
                         unsigned short* __restrict__ W1p, unsigned short* __restrict__ W2p,
                         float* __restrict__ sh1, float* __restrict__ sh2) {
    int t = blockIdx.x * blockDim.x + threadIdx.x;       // 0..32767
    if (t < 256 * 64) {                                  // W1p: n = t/64, k' = t%64
        int n = t >> 6, kp = t & 63;
        int r = kp & 3, aa = (kp >> 2) & 1, gg = (kp >> 3) & 3, T = kp >> 5;
        int k = T * 32 + aa * 16 + gg * 4 + r;
        float sc = g1[n] * rsqrtf(rv1[n] + BN_EPS);
        W1p[t] = f2bf(W1[k * 256 + n] * sc);
    }
    {                                                    // W2p: n = t/256, k' = t%256
        int n = t >> 8, kp = t & 255;
        int r = kp & 3, aa = (kp >> 2) & 1, gg = (kp >> 3) & 3, T = kp >> 5;
        int k = T * 32 + aa * 16 + gg * 4 + r;
        float sc = g2[n] * rsqrtf(rv2[n] + BN_EPS);
        W2p[t] = f2bf(W2[k * 128 + n] * sc);
    }
    if (t < 256) {
        float s = g1[t] * rsqrtf(rv1[t] + BN_EPS);
        sh1[t] = (b1[t] - rm1[t]) * s + be1[t];
    }
    if (t < 128) {
        float s = g2[t] * rsqrtf(rv2[t] + BN_EPS);
        sh2[t] = (b2[t] - rm2[t]) * s + be2[t];
    }
}

// ---------------- main fused kernel ----------------
// LDS (18944 B): vtt [64][136]u16 @0 (17408) | sh1 f32[256] @17408 | sh2 f32[128] @18432
__global__ void __launch_bounds__(256, 4)
gcn_main(const float* __restrict__ A, const float* __restrict__ V,
         const unsigned short* __restrict__ W1p, const unsigned short* __restrict__ W2p,
         const float* __restrict__ sh1g, const float* __restrict__ sh2g,
         float* __restrict__ out) {
    __shared__ char smem[18944];
    unsigned short* s_vtt = (unsigned short*)smem;        // [64][136]: vtt[c][m] = bf16(v[m][c]*dinv[m])
    float* s_sh1 = (float*)(smem + 17408);
    float* s_sh2 = (float*)(smem + 18432);

    const int t    = threadIdx.x;
    const int lane = t & 63;
    const int w    = t >> 6;       // wave owns rows 32w..32w+31
    const int r16  = lane & 15;
    const int g    = lane >> 4;
    const int b    = blockIdx.x;

    s_sh1[t] = sh1g[t];
    if (t < 128) s_sh2[t] = sh2g[t];

    // ---- V loads (own 32 rows), issued early ----
    const int mloc  = lane & 31;
    const int chalf = (lane >> 5) * 32;
    const float* vb = V + (size_t)b * 8192 + (size_t)(32 * w + mloc) * 64 + chalf;
    f32x4 pv[8];
#pragma unroll
    for (int q = 0; q < 8; ++q) pv[q] = *(const f32x4*)(vb + 4 * q);

    // ---- A: own 32 rows -> threshold into fragments + degree ----
    const float* ab = A + (size_t)b * 16384 + (size_t)(32 * w + r16) * 128;
    bf16x8 afrag[2][4];     // [mt][ks]: a_th[row=32w+16mt+r16][col=32ks+8g+j]
    int cnt0 = 0, cnt1 = 0;
#pragma unroll
    for (int mt = 0; mt < 2; ++mt)
#pragma unroll
        for (int ks = 0; ks < 4; ++ks) {
            const float* p = ab + mt * 2048 + ks * 32 + 8 * g;
            f32x4 x0 = *(const f32x4*)p;
            f32x4 x1 = *(const f32x4*)(p + 4);
            union { unsigned short s[8]; bf16x8 v; } u;
            u.s[0] = (x0.x >= THRESH) ? (unsigned short)0x3F80u : (unsigned short)0u;
            u.s[1] = (x0.y >= THRESH) ? (unsigned short)0x3F80u : (unsigned short)0u;
            u.s[2] = (x0.z >= THRESH) ? (unsigned short)0x3F80u : (unsigned short)0u;
            u.s[3] = (x0.w >= THRESH) ? (unsigned short)0x3F80u : (unsigned short)0u;
            u.s[4] = (x1.x >= THRESH) ? (unsigned short)0x3F80u : (unsigned short)0u;
            u.s[5] = (x1.y >= THRESH) ? (unsigned short)0x3F80u : (unsigned short)0u;
            u.s[6] = (x1.z >= THRESH) ? (unsigned short)0x3F80u : (unsigned short)0u;
            u.s[7] = (x1.w >= THRESH) ? (unsigned short)0x3F80u : (unsigned short)0u;
            afrag[mt][ks] = u.v;
            int c = (x0.x >= THRESH) + (x0.y >= THRESH) + (x0.z >= THRESH) + (x0.w >= THRESH)
                  + (x1.x >= THRESH) + (x1.y >= THRESH) + (x1.z >= THRESH) + (x1.w >= THRESH);
            if (mt == 0) cnt0 += c; else cnt1 += c;
        }
    cnt0 += __shfl_xor(cnt0, 16); cnt0 += __shfl_xor(cnt0, 32);
    cnt1 += __shfl_xor(cnt1, 16); cnt1 += __shfl_xor(cnt1, 32);
    const float dinv0 = rsqrtf((float)cnt0);   // row 32w + r16       (all lanes)
    const float dinv1 = rsqrtf((float)cnt1);   // row 32w + 16 + r16  (all lanes)

    // ---- vtt[c][m] = bf16(v[m][c] * dinv[m]) for own m (dinv register-local) ----
    {
        float dm = (lane & 16) ? dinv1 : dinv0;   // mloc = (lane&16) + r16
        int m = 32 * w + mloc;
#pragma unroll
        for (int q = 0; q < 8; ++q) {
            int c = chalf + 4 * q;
            s_vtt[(c + 0) * 136 + m] = f2bf(pv[q].x * dm);
            s_vtt[(c + 1) * 136 + m] = f2bf(pv[q].y * dm);
            s_vtt[(c + 2) * 136 + m] = f2bf(pv[q].z * dm);
            s_vtt[(c + 3) * 136 + m] = f2bf(pv[q].w * dm);
        }
    }
    __syncthreads();   // the ONLY block barrier: vtt published

    // ---- GEMM1 (transposed): h^T = v̂^T @ a_th^T.  A = vtt-frag, B = afrag. ----
    // D[ct][mt]: h_pre[m = 32w+16mt+r16][c = 16ct+4g+r]  (m lane-local!)
    f32x4 acc1[4][2];
#pragma unroll
    for (int ct = 0; ct < 4; ++ct)
#pragma unroll
        for (int mt = 0; mt < 2; ++mt) acc1[ct][mt] = f32x4{0.f, 0.f, 0.f, 0.f};
#pragma unroll
    for (int ks = 0; ks < 4; ++ks)
#pragma unroll
        for (int ct = 0; ct < 4; ++ct) {
            bf16x8 av = *(const bf16x8*)(s_vtt + (ct * 16 + r16) * 136 + ks * 32 + 8 * g);
            acc1[ct][0] = __builtin_amdgcn_mfma_f32_16x16x32_bf16(av, afrag[0][ks], acc1[ct][0], 0, 0, 0);
            acc1[ct][1] = __builtin_amdgcn_mfma_f32_16x16x32_bf16(av, afrag[1][ks], acc1[ct][1], 0, 0, 0);
        }

    // ---- h = dinv[m] * h_pre -> bf16 B-frags for GEMM2 (k-bijection pack) ----
    // bh[mt][ks2] slot j = h[m][c = 32ks2 + 16(j>>2) + 4g + (j&3)]
    bf16x8 bh[2][2];
#pragma unroll
    for (int mt = 0; mt < 2; ++mt) {
        float d = (mt == 0) ? dinv0 : dinv1;
#pragma unroll
        for (int ks2 = 0; ks2 < 2; ++ks2) {
            union { unsigned u[4]; bf16x8 v; } pk;
            pk.u[0] = cvt_pk(acc1[2 * ks2][mt][0] * d,     acc1[2 * ks2][mt][1] * d);
            pk.u[1] = cvt_pk(acc1[2 * ks2][mt][2] * d,     acc1[2 * ks2][mt][3] * d);
            pk.u[2] = cvt_pk(acc1[2 * ks2 + 1][mt][0] * d, acc1[2 * ks2 + 1][mt][1] * d);
            pk.u[3] = cvt_pk(acc1[2 * ks2 + 1][mt][2] * d, acc1[2 * ks2 + 1][mt][3] * d);
            bh[mt][ks2] = pk.v;
        }
    }

    // ---- fused GEMM2 (x1^T) + BN1-shift/ReLU + GEMM3 ----
    f32x4 acc3[2][8];
#pragma unroll
    for (int mt = 0; mt < 2; ++mt)
#pragma unroll
        for (int ct = 0; ct < 8; ++ct) acc3[mt][ct] = f32x4{0.f, 0.f, 0.f, 0.f};

#pragma unroll
    for (int T = 0; T < 8; ++T) {
        // GEMM2: a2[mt][ctp][r] = x1_pre[m=32w+16mt+r16][c=(2T+ctp)*16+4g+r]
        f32x4 a2[2][2];
#pragma unroll
        for (int mt = 0; mt < 2; ++mt)
#pragma unroll
            for (int ctp = 0; ctp < 2; ++ctp) a2[mt][ctp] = f32x4{0.f, 0.f, 0.f, 0.f};
#pragma unroll
        for (int ctp = 0; ctp < 2; ++ctp) {
            int ct = 2 * T + ctp;
#pragma unroll
            for (int ks2 = 0; ks2 < 2; ++ks2) {
                bf16x8 aw = *(const bf16x8*)(W1p + (ct * 16 + r16) * 64 + ks2 * 32 + 8 * g);
                a2[0][ctp] = __builtin_amdgcn_mfma_f32_16x16x32_bf16(aw, bh[0][ks2], a2[0][ctp], 0, 0, 0);
                a2[1][ctp] = __builtin_amdgcn_mfma_f32_16x16x32_bf16(aw, bh[1][ks2], a2[1][ctp], 0, 0, 0);
            }
        }
        // BN1 shift + ReLU + bijection pack -> GEMM3 A-frags
        unsigned wds[2][4];
#pragma unroll
        for (int ctp = 0; ctp < 2; ++ctp) {
            f32x4 sh = *(const f32x4*)(s_sh1 + (2 * T + ctp) * 16 + 4 * g);
#pragma unroll
            for (int mt = 0; mt < 2; ++mt) {
                float y0 = fmaxf(a2[mt][ctp][0] + sh.x, 0.f);
                float y1 = fmaxf(a2[mt][ctp][1] + sh.y, 0.f);
                float y2 = fmaxf(a2[mt][ctp][2] + sh.z, 0.f);
                float y3 = fmaxf(a2[mt][ctp][3] + sh.w, 0.f);
                wds[mt][2 * ctp + 0] = cvt_pk(y0, y1);
                wds[mt][2 * ctp + 1] = cvt_pk(y2, y3);
            }
        }
        // GEMM3 partial over k' = 32T..32T+31
#pragma unroll
        for (int mt = 0; mt < 2; ++mt) {
            union { unsigned u[4]; bf16x8 v; } af;
            af.u[0] = wds[mt][0]; af.u[1] = wds[mt][1];
            af.u[2] = wds[mt][2]; af.u[3] = wds[mt][3];
#pragma unroll
            for (int ct3 = 0; ct3 < 8; ++ct3) {
                bf16x8 bw = *(const bf16x8*)(W2p + (ct3 * 16 + r16) * 256 + T * 32 + 8 * g);
                acc3[mt][ct3] = __builtin_amdgcn_mfma_f32_16x16x32_bf16(af.v, bw, acc3[mt][ct3], 0, 0, 0);
            }
        }
    }

    // ---- BN2 shift + ReLU -> global ----
    float* ob = out + (size_t)b * 16384;
#pragma unroll
    for (int ct3 = 0; ct3 < 8; ++ct3) {
        int c = ct3 * 16 + r16;
        float sh = s_sh2[c];
#pragma unroll
        for (int mt = 0; mt < 2; ++mt)
#pragma unroll
            for (int r = 0; r < 4; ++r) {
                int row = 32 * w + 16 * mt + 4 * g + r;
                ob[row * 128 + c] = fmaxf(acc3[mt][ct3][r] + sh, 0.f);
            }
    }
}

extern "C" void kernel_launch(void* const* d_in, const int* in_sizes, int n_in,
                              void* d_out, int out_size, void* d_ws, size_t ws_size,
                              hipStream_t stream) {
    (void)in_sizes; (void)n_in; (void)out_size; (void)ws_size;
    const float* a   = (const float*)d_in[0];
    const float* v   = (const float*)d_in[1];
    const float* W1  = (const float*)d_in[2];
    const float* b1  = (const float*)d_in[3];
    const float* g1  = (const float*)d_in[4];
    const float* be1 = (const float*)d_in[5];
    const float* rm1 = (const float*)d_in[6];
    const float* rv1 = (const float*)d_in[7];
    const float* W2  = (const float*)d_in[8];
    const float* b2  = (const float*)d_in[9];
    const float* g2  = (const float*)d_in[10];
    const float* be2 = (const float*)d_in[11];
    const float* rm2 = (const float*)d_in[12];
    const float* rv2 = (const float*)d_in[13];

    char* ws = (char*)d_ws;
    unsigned short* W1p = (unsigned short*)ws;             // 32768 B
    unsigned short* W2p = (unsigned short*)(ws + 32768);   // 65536 B
    float* sh1 = (float*)(ws + 98304);                     // 1024 B
    float* sh2 = (float*)(ws + 99328);                     // 512 B

    gcn_prep<<<128, 256, 0, stream>>>(W1, b1, g1, be1, rm1, rv1,
                                      W2, b2, g2, be2, rm2, rv2,
                                      W1p, W2p, sh1, sh2);
    gcn_main<<<4096, 256, 0, stream>>>(a, v, W1p, W2p, sh1, sh2, (float*)d_out);
}

// Round 5
// 380.972 us; speedup vs baseline: 1.1671x; 1.1671x over previous
//
#include <hip/hip_runtime.h>

// LayerGCN: out = relu(bn2(relu(bn1( (D^-.5 (A>=.1) D^-.5) V @ W1 )) @ W2))
// B=4096, N=128, C_IN=64, C_HID=256, C_OUT=128.
// R5: two streaming kernels. gcn_prop: A,V -> hP (bf16, bijection-packed) with
// transposed GEMM1, regs ~85, 5 blocks/CU. gcn_mlp: hP -> out, R4's register
// T-loop, col-split waves (acc3 halved), 4 blocks/CU. h lives in ws (64MB, L3).

#define THRESH 0.1f
#define BN_EPS 1e-5f

typedef __attribute__((ext_vector_type(8))) short bf16x8;
typedef __attribute__((ext_vector_type(4))) float f32x4;

__device__ __forceinline__ unsigned short f2bf(float f) {
    union { float f; unsigned u; } x; x.f = f;
    unsigned r = x.u + 0x7FFFu + ((x.u >> 16) & 1u);   // RNE
    return (unsigned short)(r >> 16);
}

__device__ __forceinline__ unsigned cvt_pk(float lo, float hi) {
    unsigned r;
    asm("v_cvt_pk_bf16_f32 %0, %1, %2" : "=v"(r) : "v"(lo), "v"(hi));
    return r;
}

// ---------------- prep ----------------
// Shared k-bijection within each 32-chunk: k' fields {T=k'>>5, gg=(k'>>3)&3,
// a=(k'>>2)&1, r=k'&3} <-> k = 32T + 16a + 4gg + r. Register slot j of lane-group
// g holds logical k = 32T + 16(j>>2) + 4g + (j&3); contiguous-8 load of k' matches.
// W1p[n][k'] = bf16(W1[k][n]*sc1[n]) (256x64), W2p[n][k'] = bf16(W2[k][n]*sc2[n]) (128x256)
__global__ void gcn_prep(const float* __restrict__ W1, const float* __restrict__ b1,
                         const float* __restrict__ g1, const float* __restrict__ be1,
                         const float* __restrict__ rm1, const float* __restrict__ rv1,
                         const float* __restrict__ W2, const float* __restrict__ b2,
                         const float* __restrict__ g2, const float* __restrict__ be2,
                         const float* __restrict__ rm2, const float* __restrict__ rv2,
                         unsigned short* __restrict__ W1p, unsigned short* __restrict__ W2p,
                         float* __restrict__ sh1, float* __restrict__ sh2) {
    int t = blockIdx.x * blockDim.x + threadIdx.x;       // 0..32767
    if (t < 256 * 64) {
        int n = t >> 6, kp = t & 63;
        int r = kp & 3, aa = (kp >> 2) & 1, gg = (kp >> 3) & 3, T = kp >> 5;
        int k = T * 32 + aa * 16 + gg * 4 + r;
        float sc = g1[n] * rsqrtf(rv1[n] + BN_EPS);
        W1p[t] = f2bf(W1[k * 256 + n] * sc);
    }
    {
        int n = t >> 8, kp = t & 255;
        int r = kp & 3, aa = (kp >> 2) & 1, gg = (kp >> 3) & 3, T = kp >> 5;
        int k = T * 32 + aa * 16 + gg * 4 + r;
        float sc = g2[n] * rsqrtf(rv2[n] + BN_EPS);
        W2p[t] = f2bf(W2[k * 128 + n] * sc);
    }
    if (t < 256) {
        float s = g1[t] * rsqrtf(rv1[t] + BN_EPS);
        sh1[t] = (b1[t] - rm1[t]) * s + be1[t];
    }
    if (t < 128) {
        float s = g2[t] * rsqrtf(rv2[t] + BN_EPS);
        sh2[t] = (b2[t] - rm2[t]) * s + be2[t];
    }
}

// ---------------- kernel 1: propagate  A,V -> hP ----------------
// hP[m][c'] bf16, c' bijection-packed so gcn_mlp's contiguous bf16x8 load at
// (m*64 + ks2*32 + 8g) reproduces R4's bh fragment exactly.
// LDS: vtt [64][136]u16 (17408 B) only.
__global__ void __launch_bounds__(256, 5)
gcn_prop(const float* __restrict__ A, const float* __restrict__ V,
         unsigned short* __restrict__ hP) {
    __shared__ unsigned short s_vtt[64 * 136];   // vtt[c][m] = bf16(v[m][c]*dinv[m])

    const int t    = threadIdx.x;
    const int lane = t & 63;
    const int w    = t >> 6;       // wave owns rows 32w..32w+31
    const int r16  = lane & 15;
    const int g    = lane >> 4;
    const int b    = blockIdx.x;

    // V loads (own 32 rows), issued early
    const int mloc  = lane & 31;
    const int chalf = (lane >> 5) * 32;
    const float* vb = V + (size_t)b * 8192 + (size_t)(32 * w + mloc) * 64 + chalf;
    f32x4 pv[8];
#pragma unroll
    for (int q = 0; q < 8; ++q) pv[q] = *(const f32x4*)(vb + 4 * q);

    // A: own 32 rows -> threshold fragments + degree
    const float* ab = A + (size_t)b * 16384 + (size_t)(32 * w + r16) * 128;
    bf16x8 afrag[2][4];     // [mt][ks]: a_th[row=32w+16mt+r16][col=32ks+8g+j]
    int cnt0 = 0, cnt1 = 0;
#pragma unroll
    for (int mt = 0; mt < 2; ++mt)
#pragma unroll
        for (int ks = 0; ks < 4; ++ks) {
            const float* p = ab + mt * 2048 + ks * 32 + 8 * g;
            f32x4 x0 = *(const f32x4*)p;
            f32x4 x1 = *(const f32x4*)(p + 4);
            union { unsigned short s[8]; bf16x8 v; } u;
            u.s[0] = (x0.x >= THRESH) ? (unsigned short)0x3F80u : (unsigned short)0u;
            u.s[1] = (x0.y >= THRESH) ? (unsigned short)0x3F80u : (unsigned short)0u;
            u.s[2] = (x0.z >= THRESH) ? (unsigned short)0x3F80u : (unsigned short)0u;
            u.s[3] = (x0.w >= THRESH) ? (unsigned short)0x3F80u : (unsigned short)0u;
            u.s[4] = (x1.x >= THRESH) ? (unsigned short)0x3F80u : (unsigned short)0u;
            u.s[5] = (x1.y >= THRESH) ? (unsigned short)0x3F80u : (unsigned short)0u;
            u.s[6] = (x1.z >= THRESH) ? (unsigned short)0x3F80u : (unsigned short)0u;
            u.s[7] = (x1.w >= THRESH) ? (unsigned short)0x3F80u : (unsigned short)0u;
            afrag[mt][ks] = u.v;
            int c = (x0.x >= THRESH) + (x0.y >= THRESH) + (x0.z >= THRESH) + (x0.w >= THRESH)
                  + (x1.x >= THRESH) + (x1.y >= THRESH) + (x1.z >= THRESH) + (x1.w >= THRESH);
            if (mt == 0) cnt0 += c; else cnt1 += c;
        }
    cnt0 += __shfl_xor(cnt0, 16); cnt0 += __shfl_xor(cnt0, 32);
    cnt1 += __shfl_xor(cnt1, 16); cnt1 += __shfl_xor(cnt1, 32);
    const float dinv0 = rsqrtf((float)cnt0);   // row 32w + r16
    const float dinv1 = rsqrtf((float)cnt1);   // row 32w + 16 + r16

    // vtt[c][m] = bf16(v[m][c] * dinv[m]) for own m
    {
        float dm = (lane & 16) ? dinv1 : dinv0;
        int m = 32 * w + mloc;
#pragma unroll
        for (int q = 0; q < 8; ++q) {
            int c = chalf + 4 * q;
            s_vtt[(c + 0) * 136 + m] = f2bf(pv[q].x * dm);
            s_vtt[(c + 1) * 136 + m] = f2bf(pv[q].y * dm);
            s_vtt[(c + 2) * 136 + m] = f2bf(pv[q].z * dm);
            s_vtt[(c + 3) * 136 + m] = f2bf(pv[q].w * dm);
        }
    }
    __syncthreads();

    // GEMM1 (transposed): D[ct][mt] = h_pre[m=32w+16mt+r16][c=16ct+4g+r]
    f32x4 acc1[4][2];
#pragma unroll
    for (int ct = 0; ct < 4; ++ct)
#pragma unroll
        for (int mt = 0; mt < 2; ++mt) acc1[ct][mt] = f32x4{0.f, 0.f, 0.f, 0.f};
#pragma unroll
    for (int ks = 0; ks < 4; ++ks)
#pragma unroll
        for (int ct = 0; ct < 4; ++ct) {
            bf16x8 av = *(const bf16x8*)(s_vtt + (ct * 16 + r16) * 136 + ks * 32 + 8 * g);
            acc1[ct][0] = __builtin_amdgcn_mfma_f32_16x16x32_bf16(av, afrag[0][ks], acc1[ct][0], 0, 0, 0);
            acc1[ct][1] = __builtin_amdgcn_mfma_f32_16x16x32_bf16(av, afrag[1][ks], acc1[ct][1], 0, 0, 0);
        }

    // h = dinv[m]*h_pre -> bijection-packed bf16x8, stored to hP
    // (identical register values to R4's bh[mt][ks2])
#pragma unroll
    for (int mt = 0; mt < 2; ++mt) {
        float d = (mt == 0) ? dinv0 : dinv1;
        size_t m = (size_t)(b * 128 + 32 * w + 16 * mt + r16);
#pragma unroll
        for (int ks2 = 0; ks2 < 2; ++ks2) {
            union { unsigned u[4]; bf16x8 v; } pk;
            pk.u[0] = cvt_pk(acc1[2 * ks2][mt][0] * d,     acc1[2 * ks2][mt][1] * d);
            pk.u[1] = cvt_pk(acc1[2 * ks2][mt][2] * d,     acc1[2 * ks2][mt][3] * d);
            pk.u[2] = cvt_pk(acc1[2 * ks2 + 1][mt][0] * d, acc1[2 * ks2 + 1][mt][1] * d);
            pk.u[3] = cvt_pk(acc1[2 * ks2 + 1][mt][2] * d, acc1[2 * ks2 + 1][mt][3] * d);
            *(bf16x8*)(hP + m * 64 + ks2 * 32 + 8 * g) = pk.v;
        }
    }
}

// ---------------- kernel 2: MLP  hP -> out ----------------
// Block: 64 rows. Wave w: row-group rg=w&1 (rows 32rg..32rg+31), col-half ch=w>>1
// (out cols 64ch..64ch+63). acc3 halved to [2][4].
__global__ void __launch_bounds__(256, 4)
gcn_mlp(const unsigned short* __restrict__ hP,
        const unsigned short* __restrict__ W1p, const unsigned short* __restrict__ W2p,
        const float* __restrict__ sh1g, const float* __restrict__ sh2g,
        float* __restrict__ out) {
    __shared__ float s_sh1[256];
    __shared__ float s_sh2[128];

    const int t    = threadIdx.x;
    const int lane = t & 63;
    const int w    = t >> 6;
    const int r16  = lane & 15;
    const int g    = lane >> 4;
    const int rg   = w & 1;
    const int ch   = w >> 1;
    const size_t mbase = (size_t)blockIdx.x * 64 + 32 * rg;

    s_sh1[t] = sh1g[t];
    if (t < 128) s_sh2[t] = sh2g[t];
    __syncthreads();

    // h fragments (B-operand) straight from hP (L3-resident)
    bf16x8 bh[2][2];
#pragma unroll
    for (int mt = 0; mt < 2; ++mt)
#pragma unroll
        for (int ks2 = 0; ks2 < 2; ++ks2)
            bh[mt][ks2] = *(const bf16x8*)(hP + (mbase + 16 * mt + r16) * 64 + ks2 * 32 + 8 * g);

    f32x4 acc3[2][4];
#pragma unroll
    for (int mt = 0; mt < 2; ++mt)
#pragma unroll
        for (int q = 0; q < 4; ++q) acc3[mt][q] = f32x4{0.f, 0.f, 0.f, 0.f};

#pragma unroll
    for (int T = 0; T < 8; ++T) {
        // GEMM2: a2[mt][ctp][r] = x1_pre[m=mbase+16mt+r16][c=(2T+ctp)*16+4g+r]
        f32x4 a2[2][2];
#pragma unroll
        for (int mt = 0; mt < 2; ++mt)
#pragma unroll
            for (int ctp = 0; ctp < 2; ++ctp) a2[mt][ctp] = f32x4{0.f, 0.f, 0.f, 0.f};
#pragma unroll
        for (int ctp = 0; ctp < 2; ++ctp) {
            int ct = 2 * T + ctp;
#pragma unroll
            for (int ks2 = 0; ks2 < 2; ++ks2) {
                bf16x8 aw = *(const bf16x8*)(W1p + (ct * 16 + r16) * 64 + ks2 * 32 + 8 * g);
                a2[0][ctp] = __builtin_amdgcn_mfma_f32_16x16x32_bf16(aw, bh[0][ks2], a2[0][ctp], 0, 0, 0);
                a2[1][ctp] = __builtin_amdgcn_mfma_f32_16x16x32_bf16(aw, bh[1][ks2], a2[1][ctp], 0, 0, 0);
            }
        }
        // BN1 shift + ReLU + bijection pack -> GEMM3 A-frags
        unsigned wds[2][4];
#pragma unroll
        for (int ctp = 0; ctp < 2; ++ctp) {
            f32x4 sh = *(const f32x4*)(s_sh1 + (2 * T + ctp) * 16 + 4 * g);
#pragma unroll
            for (int mt = 0; mt < 2; ++mt) {
                float y0 = fmaxf(a2[mt][ctp][0] + sh.x, 0.f);
                float y1 = fmaxf(a2[mt][ctp][1] + sh.y, 0.f);
                float y2 = fmaxf(a2[mt][ctp][2] + sh.z, 0.f);
                float y3 = fmaxf(a2[mt][ctp][3] + sh.w, 0.f);
                wds[mt][2 * ctp + 0] = cvt_pk(y0, y1);
                wds[mt][2 * ctp + 1] = cvt_pk(y2, y3);
            }
        }
        // GEMM3 partial over k' = 32T..32T+31, this wave's 4 col-tiles
#pragma unroll
        for (int mt = 0; mt < 2; ++mt) {
            union { unsigned u[4]; bf16x8 v; } af;
            af.u[0] = wds[mt][0]; af.u[1] = wds[mt][1];
            af.u[2] = wds[mt][2]; af.u[3] = wds[mt][3];
#pragma unroll
            for (int q = 0; q < 4; ++q) {
                int ct3 = ch * 4 + q;
                bf16x8 bw = *(const bf16x8*)(W2p + (ct3 * 16 + r16) * 256 + T * 32 + 8 * g);
                acc3[mt][q] = __builtin_amdgcn_mfma_f32_16x16x32_bf16(af.v, bw, acc3[mt][q], 0, 0, 0);
            }
        }
    }

    // BN2 shift + ReLU -> global
    float* ob = out + mbase * 128;
#pragma unroll
    for (int q = 0; q < 4; ++q) {
        int c = (ch * 4 + q) * 16 + r16;
        float sh = s_sh2[c];
#pragma unroll
        for (int mt = 0; mt < 2; ++mt)
#pragma unroll
            for (int r = 0; r < 4; ++r) {
                int row = 16 * mt + 4 * g + r;
                ob[row * 128 + c] = fmaxf(acc3[mt][q][r] + sh, 0.f);
            }
    }
}

extern "C" void kernel_launch(void* const* d_in, const int* in_sizes, int n_in,
                              void* d_out, int out_size, void* d_ws, size_t ws_size,
                              hipStream_t stream) {
    (void)in_sizes; (void)n_in; (void)out_size; (void)ws_size;
    const float* a   = (const float*)d_in[0];
    const float* v   = (const float*)d_in[1];
    const float* W1  = (const float*)d_in[2];
    const float* b1  = (const float*)d_in[3];
    const float* g1  = (const float*)d_in[4];
    const float* be1 = (const float*)d_in[5];
    const float* rm1 = (const float*)d_in[6];
    const float* rv1 = (const float*)d_in[7];
    const float* W2  = (const float*)d_in[8];
    const float* b2  = (const float*)d_in[9];
    const float* g2  = (const float*)d_in[10];
    const float* be2 = (const float*)d_in[11];
    const float* rm2 = (const float*)d_in[12];
    const float* rv2 = (const float*)d_in[13];

    char* ws = (char*)d_ws;
    unsigned short* W1p = (unsigned short*)ws;             // 32768 B
    unsigned short* W2p = (unsigned short*)(ws + 32768);   // 65536 B
    float* sh1 = (float*)(ws + 98304);                     // 1024 B
    float* sh2 = (float*)(ws + 99328);                     // 512 B
    unsigned short* hP = (unsigned short*)(ws + 102400);   // 67108864 B (64 MB)

    gcn_prep<<<128, 256, 0, stream>>>(W1, b1, g1, be1, rm1, rv1,
                                      W2, b2, g2, be2, rm2, rv2,
                                      W1p, W2p, sh1, sh2);
    gcn_prop<<<4096, 256, 0, stream>>>(a, v, hP);
    gcn_mlp<<<8192, 256, 0, stream>>>(hP, W1p, W2p, sh1, sh2, (float*)d_out);
}

// Round 6
// 228.631 us; speedup vs baseline: 1.9448x; 1.6663x over previous
//
#include <hip/hip_runtime.h>

// LayerGCN: out = relu(bn2(relu(bn1( (D^-.5 (A>=.1) D^-.5) V @ W1 )) @ W2))
// B=4096, N=128, C_IN=64, C_HID=256, C_OUT=128.
// R6: gcn_prop unchanged (R5). gcn_mlp v2: weights in LDS (staged once/block,
// bank-swizzle baked into global layout by prep), 8-wave blocks, 128-row tiles
// x8 per block, hP prefetched a full tile ahead, zero main-loop barriers.

#define THRESH 0.1f
#define BN_EPS 1e-5f

typedef __attribute__((ext_vector_type(8))) short bf16x8;
typedef __attribute__((ext_vector_type(4))) float f32x4;

__device__ __forceinline__ unsigned short f2bf(float f) {
    union { float f; unsigned u; } x; x.f = f;
    unsigned r = x.u + 0x7FFFu + ((x.u >> 16) & 1u);   // RNE
    return (unsigned short)(r >> 16);
}

__device__ __forceinline__ unsigned cvt_pk(float lo, float hi) {
    unsigned r;
    asm("v_cvt_pk_bf16_f32 %0, %1, %2" : "=v"(r) : "v"(lo), "v"(hi));
    return r;
}

// ---------------- prep ----------------
// k-bijection within each 32-chunk (k summed -> legal): k' fields
// {T=k'>>5, gg=(k'>>3)&3, a=(k'>>2)&1, r=k'&3} <-> k = 32T + 16a + 4gg + r.
// Register slot j of lane-group g holds k = 32T + 16(j>>2) + 4g + (j&3);
// contiguous-8 load of k' matches.
// ADDITIONALLY bank-swizzled for LDS: 16B-slot s stored at sp = s ^ (n&7).
// W1s: [256][64] u16, element (n, storage kp): sp=kp>>3, s=sp^(n&7), k'=s*8+(kp&7).
// W2s: [128][256] u16, same scheme (s is 5 bits, XOR touches low 3 only).
__global__ void gcn_prep(const float* __restrict__ W1, const float* __restrict__ b1,
                         const float* __restrict__ g1, const float* __restrict__ be1,
                         const float* __restrict__ rm1, const float* __restrict__ rv1,
                         const float* __restrict__ W2, const float* __restrict__ b2,
                         const float* __restrict__ g2, const float* __restrict__ be2,
                         const float* __restrict__ rm2, const float* __restrict__ rv2,
                         unsigned short* __restrict__ W1s, unsigned short* __restrict__ W2s,
                         float* __restrict__ sh1, float* __restrict__ sh2) {
    int t = blockIdx.x * blockDim.x + threadIdx.x;       // 0..32767
    if (t < 256 * 64) {                                  // W1s: n = t/64, kp = t%64
        int n = t >> 6, kp = t & 63;
        int sp = kp >> 3, lo = kp & 7;
        int s  = sp ^ (n & 7);
        int k2 = s * 8 + lo;
        int r = k2 & 3, aa = (k2 >> 2) & 1, gg = (k2 >> 3) & 3, T = k2 >> 5;
        int k = T * 32 + aa * 16 + gg * 4 + r;
        float sc = g1[n] * rsqrtf(rv1[n] + BN_EPS);
        W1s[t] = f2bf(W1[k * 256 + n] * sc);
    }
    {                                                    // W2s: n = t/256, kp = t%256
        int n = t >> 8, kp = t & 255;
        int sp = kp >> 3, lo = kp & 7;
        int s  = sp ^ (n & 7);
        int k2 = s * 8 + lo;
        int r = k2 & 3, aa = (k2 >> 2) & 1, gg = (k2 >> 3) & 3, T = k2 >> 5;
        int k = T * 32 + aa * 16 + gg * 4 + r;
        float sc = g2[n] * rsqrtf(rv2[n] + BN_EPS);
        W2s[t] = f2bf(W2[k * 128 + n] * sc);
    }
    if (t < 256) {
        float s = g1[t] * rsqrtf(rv1[t] + BN_EPS);
        sh1[t] = (b1[t] - rm1[t]) * s + be1[t];
    }
    if (t < 128) {
        float s = g2[t] * rsqrtf(rv2[t] + BN_EPS);
        sh2[t] = (b2[t] - rm2[t]) * s + be2[t];
    }
}

// ---------------- kernel 1: propagate  A,V -> hP  (unchanged from R5) ----------------
__global__ void __launch_bounds__(256, 5)
gcn_prop(const float* __restrict__ A, const float* __restrict__ V,
         unsigned short* __restrict__ hP) {
    __shared__ unsigned short s_vtt[64 * 136];   // vtt[c][m] = bf16(v[m][c]*dinv[m])

    const int t    = threadIdx.x;
    const int lane = t & 63;
    const int w    = t >> 6;
    const int r16  = lane & 15;
    const int g    = lane >> 4;
    const int b    = blockIdx.x;

    const int mloc  = lane & 31;
    const int chalf = (lane >> 5) * 32;
    const float* vb = V + (size_t)b * 8192 + (size_t)(32 * w + mloc) * 64 + chalf;
    f32x4 pv[8];
#pragma unroll
    for (int q = 0; q < 8; ++q) pv[q] = *(const f32x4*)(vb + 4 * q);

    const float* ab = A + (size_t)b * 16384 + (size_t)(32 * w + r16) * 128;
    bf16x8 afrag[2][4];
    int cnt0 = 0, cnt1 = 0;
#pragma unroll
    for (int mt = 0; mt < 2; ++mt)
#pragma unroll
        for (int ks = 0; ks < 4; ++ks) {
            const float* p = ab + mt * 2048 + ks * 32 + 8 * g;
            f32x4 x0 = *(const f32x4*)p;
            f32x4 x1 = *(const f32x4*)(p + 4);
            union { unsigned short s[8]; bf16x8 v; } u;
            u.s[0] = (x0.x >= THRESH) ? (unsigned short)0x3F80u : (unsigned short)0u;
            u.s[1] = (x0.y >= THRESH) ? (unsigned short)0x3F80u : (unsigned short)0u;
            u.s[2] = (x0.z >= THRESH) ? (unsigned short)0x3F80u : (unsigned short)0u;
            u.s[3] = (x0.w >= THRESH) ? (unsigned short)0x3F80u : (unsigned short)0u;
            u.s[4] = (x1.x >= THRESH) ? (unsigned short)0x3F80u : (unsigned short)0u;
            u.s[5] = (x1.y >= THRESH) ? (unsigned short)0x3F80u : (unsigned short)0u;
            u.s[6] = (x1.z >= THRESH) ? (unsigned short)0x3F80u : (unsigned short)0u;
            u.s[7] = (x1.w >= THRESH) ? (unsigned short)0x3F80u : (unsigned short)0u;
            afrag[mt][ks] = u.v;
            int c = (x0.x >= THRESH) + (x0.y >= THRESH) + (x0.z >= THRESH) + (x0.w >= THRESH)
                  + (x1.x >= THRESH) + (x1.y >= THRESH) + (x1.z >= THRESH) + (x1.w >= THRESH);
            if (mt == 0) cnt0 += c; else cnt1 += c;
        }
    cnt0 += __shfl_xor(cnt0, 16); cnt0 += __shfl_xor(cnt0, 32);
    cnt1 += __shfl_xor(cnt1, 16); cnt1 += __shfl_xor(cnt1, 32);
    const float dinv0 = rsqrtf((float)cnt0);
    const float dinv1 = rsqrtf((float)cnt1);

    {
        float dm = (lane & 16) ? dinv1 : dinv0;
        int m = 32 * w + mloc;
#pragma unroll
        for (int q = 0; q < 8; ++q) {
            int c = chalf + 4 * q;
            s_vtt[(c + 0) * 136 + m] = f2bf(pv[q].x * dm);
            s_vtt[(c + 1) * 136 + m] = f2bf(pv[q].y * dm);
            s_vtt[(c + 2) * 136 + m] = f2bf(pv[q].z * dm);
            s_vtt[(c + 3) * 136 + m] = f2bf(pv[q].w * dm);
        }
    }
    __syncthreads();

    f32x4 acc1[4][2];
#pragma unroll
    for (int ct = 0; ct < 4; ++ct)
#pragma unroll
        for (int mt = 0; mt < 2; ++mt) acc1[ct][mt] = f32x4{0.f, 0.f, 0.f, 0.f};
#pragma unroll
    for (int ks = 0; ks < 4; ++ks)
#pragma unroll
        for (int ct = 0; ct < 4; ++ct) {
            bf16x8 av = *(const bf16x8*)(s_vtt + (ct * 16 + r16) * 136 + ks * 32 + 8 * g);
            acc1[ct][0] = __builtin_amdgcn_mfma_f32_16x16x32_bf16(av, afrag[0][ks], acc1[ct][0], 0, 0, 0);
            acc1[ct][1] = __builtin_amdgcn_mfma_f32_16x16x32_bf16(av, afrag[1][ks], acc1[ct][1], 0, 0, 0);
        }

#pragma unroll
    for (int mt = 0; mt < 2; ++mt) {
        float d = (mt == 0) ? dinv0 : dinv1;
        size_t m = (size_t)(b * 128 + 32 * w + 16 * mt + r16);
#pragma unroll
        for (int ks2 = 0; ks2 < 2; ++ks2) {
            union { unsigned u[4]; bf16x8 v; } pk;
            pk.u[0] = cvt_pk(acc1[2 * ks2][mt][0] * d,     acc1[2 * ks2][mt][1] * d);
            pk.u[1] = cvt_pk(acc1[2 * ks2][mt][2] * d,     acc1[2 * ks2][mt][3] * d);
            pk.u[2] = cvt_pk(acc1[2 * ks2 + 1][mt][0] * d, acc1[2 * ks2 + 1][mt][1] * d);
            pk.u[3] = cvt_pk(acc1[2 * ks2 + 1][mt][2] * d, acc1[2 * ks2 + 1][mt][3] * d);
            *(bf16x8*)(hP + m * 64 + ks2 * 32 + 8 * g) = pk.v;
        }
    }
}

// ---------------- kernel 2: MLP  hP -> out  (v2: LDS weights) ----------------
// 512 thr = 8 waves: rg=w&1 (64-row half), ch=w>>1 (32-col quarter).
// Block processes 8 consecutive 128-row tiles. LDS: W1L 32K | W2L 64K | sh 1.5K.
__global__ void __launch_bounds__(512, 2)
gcn_mlp(const unsigned short* __restrict__ hP,
        const unsigned short* __restrict__ W1s, const unsigned short* __restrict__ W2s,
        const float* __restrict__ sh1g, const float* __restrict__ sh2g,
        float* __restrict__ out) {
    __shared__ char smem[99840];
    unsigned short* W1L = (unsigned short*)smem;            // [256][64] u16, swizzled
    unsigned short* W2L = (unsigned short*)(smem + 32768);  // [128][256] u16, swizzled
    float* s_sh1 = (float*)(smem + 98304);
    float* s_sh2 = (float*)(smem + 99328);

    const int t    = threadIdx.x;
    const int lane = t & 63;
    const int w    = t >> 6;
    const int r16  = lane & 15;
    const int g    = lane >> 4;
    const int rg   = w & 1;
    const int ch   = w >> 1;

    // ---- stage weights (linear copy; swizzle already baked in) ----
#pragma unroll
    for (int q = 0; q < 4; ++q)
        *(f32x4*)(smem + t * 64 + q * 16) = *(const f32x4*)((const char*)W1s + t * 64 + q * 16);
#pragma unroll
    for (int q = 0; q < 8; ++q)
        *(f32x4*)(smem + 32768 + t * 128 + q * 16) =
            *(const f32x4*)((const char*)W2s + t * 128 + q * 16);
    if (t < 256) s_sh1[t] = sh1g[t];
    if (t < 128) s_sh2[t] = sh2g[t];
    __syncthreads();   // only barrier in the kernel

    const size_t tile0 = (size_t)blockIdx.x * 8;

    // prefetch tile 0's h fragments
    bf16x8 nb[4][2];
    {
        size_t mb = tile0 * 128 + rg * 64;
#pragma unroll
        for (int mt = 0; mt < 4; ++mt)
#pragma unroll
            for (int ks2 = 0; ks2 < 2; ++ks2)
                nb[mt][ks2] = *(const bf16x8*)(hP + (mb + 16 * mt + r16) * 64 + ks2 * 32 + 8 * g);
    }

#pragma unroll 1
    for (int i = 0; i < 8; ++i) {
        bf16x8 bh[4][2];
#pragma unroll
        for (int mt = 0; mt < 4; ++mt)
#pragma unroll
            for (int ks2 = 0; ks2 < 2; ++ks2) bh[mt][ks2] = nb[mt][ks2];

        if (i < 7) {   // issue next tile's loads; land under this tile's compute
            size_t mb = (tile0 + i + 1) * 128 + rg * 64;
#pragma unroll
            for (int mt = 0; mt < 4; ++mt)
#pragma unroll
                for (int ks2 = 0; ks2 < 2; ++ks2)
                    nb[mt][ks2] = *(const bf16x8*)(hP + (mb + 16 * mt + r16) * 64 + ks2 * 32 + 8 * g);
        }

        f32x4 acc3[4][2];
#pragma unroll
        for (int mt = 0; mt < 4; ++mt)
#pragma unroll
            for (int q = 0; q < 2; ++q) acc3[mt][q] = f32x4{0.f, 0.f, 0.f, 0.f};

#pragma unroll
        for (int T = 0; T < 8; ++T) {
            // GEMM2: a2[mt][ctp][r] = x1_pre[m = 16mt+r16 (of wave's 64 rows)][c=(2T+ctp)*16+4g+r]
            f32x4 a2[4][2];
#pragma unroll
            for (int mt = 0; mt < 4; ++mt)
#pragma unroll
                for (int ctp = 0; ctp < 2; ++ctp) a2[mt][ctp] = f32x4{0.f, 0.f, 0.f, 0.f};
#pragma unroll
            for (int ctp = 0; ctp < 2; ++ctp) {
                int ct = 2 * T + ctp;
                int n  = ct * 16 + r16;
#pragma unroll
                for (int ks2 = 0; ks2 < 2; ++ks2) {
                    int sp = (ks2 * 4 + g) ^ (n & 7);
                    bf16x8 aw = *(const bf16x8*)(W1L + n * 64 + sp * 8);
#pragma unroll
                    for (int mt = 0; mt < 4; ++mt)
                        a2[mt][ctp] = __builtin_amdgcn_mfma_f32_16x16x32_bf16(aw, bh[mt][ks2], a2[mt][ctp], 0, 0, 0);
                }
            }
            // BN1 shift + ReLU + bijection pack -> GEMM3 A-frags
            unsigned wds[4][4];
#pragma unroll
            for (int ctp = 0; ctp < 2; ++ctp) {
                f32x4 sh = *(const f32x4*)(s_sh1 + (2 * T + ctp) * 16 + 4 * g);
#pragma unroll
                for (int mt = 0; mt < 4; ++mt) {
                    float y0 = fmaxf(a2[mt][ctp][0] + sh.x, 0.f);
                    float y1 = fmaxf(a2[mt][ctp][1] + sh.y, 0.f);
                    float y2 = fmaxf(a2[mt][ctp][2] + sh.z, 0.f);
                    float y3 = fmaxf(a2[mt][ctp][3] + sh.w, 0.f);
                    wds[mt][2 * ctp + 0] = cvt_pk(y0, y1);
                    wds[mt][2 * ctp + 1] = cvt_pk(y2, y3);
                }
            }
            // GEMM3 partial over k' = 32T..32T+31 for this wave's 2 col-tiles
#pragma unroll
            for (int q = 0; q < 2; ++q) {
                int ct3 = ch * 2 + q;
                int n   = ct3 * 16 + r16;
                int sp  = (T * 4 + g) ^ (n & 7);
                bf16x8 bw = *(const bf16x8*)(W2L + n * 256 + sp * 8);
#pragma unroll
                for (int mt = 0; mt < 4; ++mt) {
                    union { unsigned u[4]; bf16x8 v; } af;
                    af.u[0] = wds[mt][0]; af.u[1] = wds[mt][1];
                    af.u[2] = wds[mt][2]; af.u[3] = wds[mt][3];
                    acc3[mt][q] = __builtin_amdgcn_mfma_f32_16x16x32_bf16(af.v, bw, acc3[mt][q], 0, 0, 0);
                }
            }
        }

        // BN2 shift + ReLU -> global
        float* ob = out + ((tile0 + i) * 128 + rg * 64) * 128;
#pragma unroll
        for (int q = 0; q < 2; ++q) {
            int c = (ch * 2 + q) * 16 + r16;
            float sh = s_sh2[c];
#pragma unroll
            for (int mt = 0; mt < 4; ++mt)
#pragma unroll
                for (int r = 0; r < 4; ++r) {
                    int row = 16 * mt + 4 * g + r;
                    ob[row * 128 + c] = fmaxf(acc3[mt][q][r] + sh, 0.f);
                }
        }
    }
}

extern "C" void kernel_launch(void* const* d_in, const int* in_sizes, int n_in,
                              void* d_out, int out_size, void* d_ws, size_t ws_size,
                              hipStream_t stream) {
    (void)in_sizes; (void)n_in; (void)out_size; (void)ws_size;
    const float* a   = (const float*)d_in[0];
    const float* v   = (const float*)d_in[1];
    const float* W1  = (const float*)d_in[2];
    const float* b1  = (const float*)d_in[3];
    const float* g1  = (const float*)d_in[4];
    const float* be1 = (const float*)d_in[5];
    const float* rm1 = (const float*)d_in[6];
    const float* rv1 = (const float*)d_in[7];
    const float* W2  = (const float*)d_in[8];
    const float* b2  = (const float*)d_in[9];
    const float* g2  = (const float*)d_in[10];
    const float* be2 = (const float*)d_in[11];
    const float* rm2 = (const float*)d_in[12];
    const float* rv2 = (const float*)d_in[13];

    char* ws = (char*)d_ws;
    unsigned short* W1s = (unsigned short*)ws;             // 32768 B
    unsigned short* W2s = (unsigned short*)(ws + 32768);   // 65536 B
    float* sh1 = (float*)(ws + 98304);                     // 1024 B
    float* sh2 = (float*)(ws + 99328);                     // 512 B
    unsigned short* hP = (unsigned short*)(ws + 102400);   // 67108864 B (64 MB)

    gcn_prep<<<128, 256, 0, stream>>>(W1, b1, g1, be1, rm1, rv1,
                                      W2, b2, g2, be2, rm2, rv2,
                                      W1s, W2s, sh1, sh2);
    gcn_prop<<<4096, 256, 0, stream>>>(a, v, hP);
    gcn_mlp<<<512, 512, 0, stream>>>(hP, W1s, W2s, sh1, sh2, (float*)d_out);
}

// Round 7
// 227.007 us; speedup vs baseline: 1.9587x; 1.0072x over previous
//
#include <hip/hip_runtime.h>

// LayerGCN: out = relu(bn2(relu(bn1( (D^-.5 (A>=.1) D^-.5) V @ W1 )) @ W2))
// B=4096, N=128, C_IN=64, C_HID=256, C_OUT=128.
// R7: gcn_prop unchanged (R5). gcn_mlp v3: LDS weights (R6) + deduplicated
// GEMM2 -- each wave owns 32 rows x full width (R4's verified T-loop), 8 waves
// = 256 rows/iter, 4 iters/block, grid 512. Zero redundant MFMA.

#define THRESH 0.1f
#define BN_EPS 1e-5f

typedef __attribute__((ext_vector_type(8))) short bf16x8;
typedef __attribute__((ext_vector_type(4))) float f32x4;

__device__ __forceinline__ unsigned short f2bf(float f) {
    union { float f; unsigned u; } x; x.f = f;
    unsigned r = x.u + 0x7FFFu + ((x.u >> 16) & 1u);   // RNE
    return (unsigned short)(r >> 16);
}

__device__ __forceinline__ unsigned cvt_pk(float lo, float hi) {
    unsigned r;
    asm("v_cvt_pk_bf16_f32 %0, %1, %2" : "=v"(r) : "v"(lo), "v"(hi));
    return r;
}

// ---------------- prep ----------------
// k-bijection within each 32-chunk (k summed -> legal): k' fields
// {T=k'>>5, gg=(k'>>3)&3, a=(k'>>2)&1, r=k'&3} <-> k = 32T + 16a + 4gg + r.
// Register slot j of lane-group g holds k = 32T + 16(j>>2) + 4g + (j&3).
// LDS bank-swizzle baked in: 16B-slot s stored at sp = s ^ (n&7).
__global__ void gcn_prep(const float* __restrict__ W1, const float* __restrict__ b1,
                         const float* __restrict__ g1, const float* __restrict__ be1,
                         const float* __restrict__ rm1, const float* __restrict__ rv1,
                         const float* __restrict__ W2, const float* __restrict__ b2,
                         const float* __restrict__ g2, const float* __restrict__ be2,
                         const float* __restrict__ rm2, const float* __restrict__ rv2,
                         unsigned short* __restrict__ W1s, unsigned short* __restrict__ W2s,
                         float* __restrict__ sh1, float* __restrict__ sh2) {
    int t = blockIdx.x * blockDim.x + threadIdx.x;       // 0..32767
    if (t < 256 * 64) {                                  // W1s: n = t/64, kp = t%64
        int n = t >> 6, kp = t & 63;
        int sp = kp >> 3, lo = kp & 7;
        int s  = sp ^ (n & 7);
        int k2 = s * 8 + lo;
        int r = k2 & 3, aa = (k2 >> 2) & 1, gg = (k2 >> 3) & 3, T = k2 >> 5;
        int k = T * 32 + aa * 16 + gg * 4 + r;
        float sc = g1[n] * rsqrtf(rv1[n] + BN_EPS);
        W1s[t] = f2bf(W1[k * 256 + n] * sc);
    }
    {                                                    // W2s: n = t/256, kp = t%256
        int n = t >> 8, kp = t & 255;
        int sp = kp >> 3, lo = kp & 7;
        int s  = sp ^ (n & 7);
        int k2 = s * 8 + lo;
        int r = k2 & 3, aa = (k2 >> 2) & 1, gg = (k2 >> 3) & 3, T = k2 >> 5;
        int k = T * 32 + aa * 16 + gg * 4 + r;
        float sc = g2[n] * rsqrtf(rv2[n] + BN_EPS);
        W2s[t] = f2bf(W2[k * 128 + n] * sc);
    }
    if (t < 256) {
        float s = g1[t] * rsqrtf(rv1[t] + BN_EPS);
        sh1[t] = (b1[t] - rm1[t]) * s + be1[t];
    }
    if (t < 128) {
        float s = g2[t] * rsqrtf(rv2[t] + BN_EPS);
        sh2[t] = (b2[t] - rm2[t]) * s + be2[t];
    }
}

// ---------------- kernel 1: propagate  A,V -> hP  (unchanged from R5) ----------------
__global__ void __launch_bounds__(256, 5)
gcn_prop(const float* __restrict__ A, const float* __restrict__ V,
         unsigned short* __restrict__ hP) {
    __shared__ unsigned short s_vtt[64 * 136];   // vtt[c][m] = bf16(v[m][c]*dinv[m])

    const int t    = threadIdx.x;
    const int lane = t & 63;
    const int w    = t >> 6;
    const int r16  = lane & 15;
    const int g    = lane >> 4;
    const int b    = blockIdx.x;

    const int mloc  = lane & 31;
    const int chalf = (lane >> 5) * 32;
    const float* vb = V + (size_t)b * 8192 + (size_t)(32 * w + mloc) * 64 + chalf;
    f32x4 pv[8];
#pragma unroll
    for (int q = 0; q < 8; ++q) pv[q] = *(const f32x4*)(vb + 4 * q);

    const float* ab = A + (size_t)b * 16384 + (size_t)(32 * w + r16) * 128;
    bf16x8 afrag[2][4];
    int cnt0 = 0, cnt1 = 0;
#pragma unroll
    for (int mt = 0; mt < 2; ++mt)
#pragma unroll
        for (int ks = 0; ks < 4; ++ks) {
            const float* p = ab + mt * 2048 + ks * 32 + 8 * g;
            f32x4 x0 = *(const f32x4*)p;
            f32x4 x1 = *(const f32x4*)(p + 4);
            union { unsigned short s[8]; bf16x8 v; } u;
            u.s[0] = (x0.x >= THRESH) ? (unsigned short)0x3F80u : (unsigned short)0u;
            u.s[1] = (x0.y >= THRESH) ? (unsigned short)0x3F80u : (unsigned short)0u;
            u.s[2] = (x0.z >= THRESH) ? (unsigned short)0x3F80u : (unsigned short)0u;
            u.s[3] = (x0.w >= THRESH) ? (unsigned short)0x3F80u : (unsigned short)0u;
            u.s[4] = (x1.x >= THRESH) ? (unsigned short)0x3F80u : (unsigned short)0u;
            u.s[5] = (x1.y >= THRESH) ? (unsigned short)0x3F80u : (unsigned short)0u;
            u.s[6] = (x1.z >= THRESH) ? (unsigned short)0x3F80u : (unsigned short)0u;
            u.s[7] = (x1.w >= THRESH) ? (unsigned short)0x3F80u : (unsigned short)0u;
            afrag[mt][ks] = u.v;
            int c = (x0.x >= THRESH) + (x0.y >= THRESH) + (x0.z >= THRESH) + (x0.w >= THRESH)
                  + (x1.x >= THRESH) + (x1.y >= THRESH) + (x1.z >= THRESH) + (x1.w >= THRESH);
            if (mt == 0) cnt0 += c; else cnt1 += c;
        }
    cnt0 += __shfl_xor(cnt0, 16); cnt0 += __shfl_xor(cnt0, 32);
    cnt1 += __shfl_xor(cnt1, 16); cnt1 += __shfl_xor(cnt1, 32);
    const float dinv0 = rsqrtf((float)cnt0);
    const float dinv1 = rsqrtf((float)cnt1);

    {
        float dm = (lane & 16) ? dinv1 : dinv0;
        int m = 32 * w + mloc;
#pragma unroll
        for (int q = 0; q < 8; ++q) {
            int c = chalf + 4 * q;
            s_vtt[(c + 0) * 136 + m] = f2bf(pv[q].x * dm);
            s_vtt[(c + 1) * 136 + m] = f2bf(pv[q].y * dm);
            s_vtt[(c + 2) * 136 + m] = f2bf(pv[q].z * dm);
            s_vtt[(c + 3) * 136 + m] = f2bf(pv[q].w * dm);
        }
    }
    __syncthreads();

    f32x4 acc1[4][2];
#pragma unroll
    for (int ct = 0; ct < 4; ++ct)
#pragma unroll
        for (int mt = 0; mt < 2; ++mt) acc1[ct][mt] = f32x4{0.f, 0.f, 0.f, 0.f};
#pragma unroll
    for (int ks = 0; ks < 4; ++ks)
#pragma unroll
        for (int ct = 0; ct < 4; ++ct) {
            bf16x8 av = *(const bf16x8*)(s_vtt + (ct * 16 + r16) * 136 + ks * 32 + 8 * g);
            acc1[ct][0] = __builtin_amdgcn_mfma_f32_16x16x32_bf16(av, afrag[0][ks], acc1[ct][0], 0, 0, 0);
            acc1[ct][1] = __builtin_amdgcn_mfma_f32_16x16x32_bf16(av, afrag[1][ks], acc1[ct][1], 0, 0, 0);
        }

#pragma unroll
    for (int mt = 0; mt < 2; ++mt) {
        float d = (mt == 0) ? dinv0 : dinv1;
        size_t m = (size_t)(b * 128 + 32 * w + 16 * mt + r16);
#pragma unroll
        for (int ks2 = 0; ks2 < 2; ++ks2) {
            union { unsigned u[4]; bf16x8 v; } pk;
            pk.u[0] = cvt_pk(acc1[2 * ks2][mt][0] * d,     acc1[2 * ks2][mt][1] * d);
            pk.u[1] = cvt_pk(acc1[2 * ks2][mt][2] * d,     acc1[2 * ks2][mt][3] * d);
            pk.u[2] = cvt_pk(acc1[2 * ks2 + 1][mt][0] * d, acc1[2 * ks2 + 1][mt][1] * d);
            pk.u[3] = cvt_pk(acc1[2 * ks2 + 1][mt][2] * d, acc1[2 * ks2 + 1][mt][3] * d);
            *(bf16x8*)(hP + m * 64 + ks2 * 32 + 8 * g) = pk.v;
        }
    }
}

// ---------------- kernel 2: MLP  hP -> out  (v3: LDS weights, dedup GEMM2) ----------------
// 512 thr = 8 waves; wave w owns rows (chunk_base + 32w .. +31), FULL width.
// Block: 4 chunks of 256 rows. LDS: W1L 32K | W2L 64K | sh 1.5K (staged once).
__global__ void __launch_bounds__(512, 2)
gcn_mlp(const unsigned short* __restrict__ hP,
        const unsigned short* __restrict__ W1s, const unsigned short* __restrict__ W2s,
        const float* __restrict__ sh1g, const float* __restrict__ sh2g,
        float* __restrict__ out) {
    __shared__ char smem[99840];
    unsigned short* W1L = (unsigned short*)smem;            // [256][64] u16, swizzled
    unsigned short* W2L = (unsigned short*)(smem + 32768);  // [128][256] u16, swizzled
    float* s_sh1 = (float*)(smem + 98304);
    float* s_sh2 = (float*)(smem + 99328);

    const int t    = threadIdx.x;
    const int lane = t & 63;
    const int w    = t >> 6;
    const int r16  = lane & 15;
    const int g    = lane >> 4;

    // ---- stage weights (linear copy; swizzle already baked in) ----
#pragma unroll
    for (int q = 0; q < 4; ++q)
        *(f32x4*)(smem + t * 64 + q * 16) = *(const f32x4*)((const char*)W1s + t * 64 + q * 16);
#pragma unroll
    for (int q = 0; q < 8; ++q)
        *(f32x4*)(smem + 32768 + t * 128 + q * 16) =
            *(const f32x4*)((const char*)W2s + t * 128 + q * 16);
    if (t < 256) s_sh1[t] = sh1g[t];
    if (t < 128) s_sh2[t] = sh2g[t];
    __syncthreads();   // only barrier in the kernel

    const size_t row00 = (size_t)blockIdx.x * 1024;   // 4 chunks x 256 rows

    // prefetch chunk 0's h fragments (wave rows: row00 + 32w + 16mt + r16)
    bf16x8 nb[2][2];
    {
        size_t mb = row00 + 32 * w;
#pragma unroll
        for (int mt = 0; mt < 2; ++mt)
#pragma unroll
            for (int ks2 = 0; ks2 < 2; ++ks2)
                nb[mt][ks2] = *(const bf16x8*)(hP + (mb + 16 * mt + r16) * 64 + ks2 * 32 + 8 * g);
    }

#pragma unroll 1
    for (int i = 0; i < 4; ++i) {
        bf16x8 bh[2][2];
#pragma unroll
        for (int mt = 0; mt < 2; ++mt)
#pragma unroll
            for (int ks2 = 0; ks2 < 2; ++ks2) bh[mt][ks2] = nb[mt][ks2];

        if (i < 3) {   // issue next chunk's loads; land under this chunk's compute
            size_t mb = row00 + (i + 1) * 256 + 32 * w;
#pragma unroll
            for (int mt = 0; mt < 2; ++mt)
#pragma unroll
                for (int ks2 = 0; ks2 < 2; ++ks2)
                    nb[mt][ks2] = *(const bf16x8*)(hP + (mb + 16 * mt + r16) * 64 + ks2 * 32 + 8 * g);
        }

        f32x4 acc3[2][8];
#pragma unroll
        for (int mt = 0; mt < 2; ++mt)
#pragma unroll
            for (int ct = 0; ct < 8; ++ct) acc3[mt][ct] = f32x4{0.f, 0.f, 0.f, 0.f};

#pragma unroll
        for (int T = 0; T < 8; ++T) {
            // GEMM2: a2[mt][ctp][r] = x1_pre[m=16mt+r16 of wave's 32 rows][c=(2T+ctp)*16+4g+r]
            f32x4 a2[2][2];
#pragma unroll
            for (int mt = 0; mt < 2; ++mt)
#pragma unroll
                for (int ctp = 0; ctp < 2; ++ctp) a2[mt][ctp] = f32x4{0.f, 0.f, 0.f, 0.f};
#pragma unroll
            for (int ctp = 0; ctp < 2; ++ctp) {
                int n = (2 * T + ctp) * 16 + r16;
#pragma unroll
                for (int ks2 = 0; ks2 < 2; ++ks2) {
                    int sp = (ks2 * 4 + g) ^ (n & 7);
                    bf16x8 aw = *(const bf16x8*)(W1L + n * 64 + sp * 8);
                    a2[0][ctp] = __builtin_amdgcn_mfma_f32_16x16x32_bf16(aw, bh[0][ks2], a2[0][ctp], 0, 0, 0);
                    a2[1][ctp] = __builtin_amdgcn_mfma_f32_16x16x32_bf16(aw, bh[1][ks2], a2[1][ctp], 0, 0, 0);
                }
            }
            // BN1 shift + ReLU + bijection pack -> GEMM3 A-frags
            unsigned wds[2][4];
#pragma unroll
            for (int ctp = 0; ctp < 2; ++ctp) {
                f32x4 sh = *(const f32x4*)(s_sh1 + (2 * T + ctp) * 16 + 4 * g);
#pragma unroll
                for (int mt = 0; mt < 2; ++mt) {
                    float y0 = fmaxf(a2[mt][ctp][0] + sh.x, 0.f);
                    float y1 = fmaxf(a2[mt][ctp][1] + sh.y, 0.f);
                    float y2 = fmaxf(a2[mt][ctp][2] + sh.z, 0.f);
                    float y3 = fmaxf(a2[mt][ctp][3] + sh.w, 0.f);
                    wds[mt][2 * ctp + 0] = cvt_pk(y0, y1);
                    wds[mt][2 * ctp + 1] = cvt_pk(y2, y3);
                }
            }
            // GEMM3 partial over k' = 32T..32T+31, full 8 col-tiles
#pragma unroll
            for (int ct3 = 0; ct3 < 8; ++ct3) {
                int n  = ct3 * 16 + r16;
                int sp = (T * 4 + g) ^ (n & 7);
                bf16x8 bw = *(const bf16x8*)(W2L + n * 256 + sp * 8);
#pragma unroll
                for (int mt = 0; mt < 2; ++mt) {
                    union { unsigned u[4]; bf16x8 v; } af;
                    af.u[0] = wds[mt][0]; af.u[1] = wds[mt][1];
                    af.u[2] = wds[mt][2]; af.u[3] = wds[mt][3];
                    acc3[mt][ct3] = __builtin_amdgcn_mfma_f32_16x16x32_bf16(af.v, bw, acc3[mt][ct3], 0, 0, 0);
                }
            }
        }

        // BN2 shift + ReLU -> global
        float* ob = out + (row00 + i * 256 + 32 * w) * 128;
#pragma unroll
        for (int ct3 = 0; ct3 < 8; ++ct3) {
            int c = ct3 * 16 + r16;
            float sh = s_sh2[c];
#pragma unroll
            for (int mt = 0; mt < 2; ++mt)
#pragma unroll
                for (int r = 0; r < 4; ++r) {
                    int row = 16 * mt + 4 * g + r;
                    ob[row * 128 + c] = fmaxf(acc3[mt][ct3][r] + sh, 0.f);
                }
        }
    }
}

extern "C" void kernel_launch(void* const* d_in, const int* in_sizes, int n_in,
                              void* d_out, int out_size, void* d_ws, size_t ws_size,
                              hipStream_t stream) {
    (void)in_sizes; (void)n_in; (void)out_size; (void)ws_size;
    const float* a   = (const float*)d_in[0];
    const float* v   = (const float*)d_in[1];
    const float* W1  = (const float*)d_in[2];
    const float* b1  = (const float*)d_in[3];
    const float* g1  = (const float*)d_in[4];
    const float* be1 = (const float*)d_in[5];
    const float* rm1 = (const float*)d_in[6];
    const float* rv1 = (const float*)d_in[7];
    const float* W2  = (const float*)d_in[8];
    const float* b2  = (const float*)d_in[9];
    const float* g2  = (const float*)d_in[10];
    const float* be2 = (const float*)d_in[11];
    const float* rm2 = (const float*)d_in[12];
    const float* rv2 = (const float*)d_in[13];

    char* ws = (char*)d_ws;
    unsigned short* W1s = (unsigned short*)ws;             // 32768 B
    unsigned short* W2s = (unsigned short*)(ws + 32768);   // 65536 B
    float* sh1 = (float*)(ws + 98304);                     // 1024 B
    float* sh2 = (float*)(ws + 99328);                     // 512 B
    unsigned short* hP = (unsigned short*)(ws + 102400);   // 67108864 B (64 MB)

    gcn_prep<<<128, 256, 0, stream>>>(W1, b1, g1, be1, rm1, rv1,
                                      W2, b2, g2, be2, rm2, rv2,
                                      W1s, W2s, sh1, sh2);
    gcn_prop<<<4096, 256, 0, stream>>>(a, v, hP);
    gcn_mlp<<<512, 512, 0, stream>>>(hP, W1s, W2s, sh1, sh2, (float*)d_out);
}